// Round 2
// 884.563 us; speedup vs baseline: 1.2203x; 1.2203x over previous
//
#include <hip/hip_runtime.h>
#include <hip/hip_bf16.h>

#define BB   2
#define SS   2048
#define DD   2048
#define HH   16
#define DHH  128
#define DFF  8192
#define MM   (BB*SS)   // 4096 tokens
#define QKD  6144      // fused qkv row width

typedef __hip_bfloat16 bf16;
typedef __bf16 bf16x8 __attribute__((ext_vector_type(8)));
typedef float  f32x4 __attribute__((ext_vector_type(4)));

// -------- async global->LDS, 16B per lane; lds base must be wave-uniform --------
__device__ __forceinline__ void gl2lds16(const void* g, void* lds_uniform_base) {
    __builtin_amdgcn_global_load_lds(
        (const __attribute__((address_space(1))) void*)g,
        (__attribute__((address_space(3))) void*)lds_uniform_base,
        16, 0, 0);
}

// ---------------------------------------------------------------------------
// LayerNorm: one block per row (D=2048), 256 threads, fp32 in -> bf16 out
// ---------------------------------------------------------------------------
__global__ __launch_bounds__(256) void ln_kernel(const float* __restrict__ x,
                                                 const float* __restrict__ g,
                                                 const float* __restrict__ b,
                                                 bf16* __restrict__ out) {
    int row = blockIdx.x, tid = threadIdx.x;
    const float4* xr = (const float4*)(x + (size_t)row * DD);
    float4 v0 = xr[tid];
    float4 v1 = xr[tid + 256];
    float s  = v0.x + v0.y + v0.z + v0.w + v1.x + v1.y + v1.z + v1.w;
    float s2 = v0.x*v0.x + v0.y*v0.y + v0.z*v0.z + v0.w*v0.w
             + v1.x*v1.x + v1.y*v1.y + v1.z*v1.z + v1.w*v1.w;
    #pragma unroll
    for (int m = 32; m >= 1; m >>= 1) { s += __shfl_xor(s, m); s2 += __shfl_xor(s2, m); }
    __shared__ float red[8];
    int wv = tid >> 6;
    if ((tid & 63) == 0) { red[wv] = s; red[wv + 4] = s2; }
    __syncthreads();
    s  = red[0] + red[1] + red[2] + red[3];
    s2 = red[4] + red[5] + red[6] + red[7];
    float mean = s * (1.0f / DD);
    float rs = rsqrtf(s2 * (1.0f / DD) - mean * mean + 1e-5f);
    bf16* o = out + (size_t)row * DD;
    int c0 = tid * 4, c1 = (tid + 256) * 4;
    float a0[4] = {v0.x, v0.y, v0.z, v0.w};
    float a1[4] = {v1.x, v1.y, v1.z, v1.w};
    #pragma unroll
    for (int j = 0; j < 4; j++) {
        o[c0 + j] = __float2bfloat16((a0[j] - mean) * rs * g[c0 + j] + b[c0 + j]);
        o[c1 + j] = __float2bfloat16((a1[j] - mean) * rs * g[c1 + j] + b[c1 + j]);
    }
}

// ---------------------------------------------------------------------------
// Transpose + fp32->bf16 cast: W[K][N] -> Wt[N][K]
// ---------------------------------------------------------------------------
__global__ __launch_bounds__(256) void transpose_cast(const float* __restrict__ W,
                                                      bf16* __restrict__ Wt,
                                                      int K, int N) {
    __shared__ float t[32][33];
    int n0 = blockIdx.x * 32, k0 = blockIdx.y * 32;
    int tx = threadIdx.x, ty = threadIdx.y;
    #pragma unroll
    for (int i = 0; i < 4; i++)
        t[ty + i * 8][tx] = W[(size_t)(k0 + ty + i * 8) * N + n0 + tx];
    __syncthreads();
    #pragma unroll
    for (int i = 0; i < 4; i++)
        Wt[(size_t)(n0 + ty + i * 8) * K + k0 + tx] = __float2bfloat16(t[tx][ty + i * 8]);
}

// ---------------------------------------------------------------------------
// concat 3 bias vectors (2048 each) into one 6144 buffer
// ---------------------------------------------------------------------------
__global__ __launch_bounds__(256) void concat3(const float* __restrict__ a,
                                               const float* __restrict__ b,
                                               const float* __restrict__ c,
                                               float* __restrict__ o) {
    int i = blockIdx.x * 256 + threadIdx.x;
    o[i] = i < 2048 ? a[i] : (i < 4096 ? b[i - 2048] : c[i - 4096]);
}

// ---------------------------------------------------------------------------
// V transpose per head from fused qkv
// ---------------------------------------------------------------------------
__global__ __launch_bounds__(256) void transpose_v(const bf16* __restrict__ qkv,
                                                   bf16* __restrict__ vt) {
    __shared__ bf16 t[32][33];
    int s0 = blockIdx.x * 32, d0 = blockIdx.y * 32;
    int bh = blockIdx.z;
    int b = bh >> 4, h = bh & 15;
    int tx = threadIdx.x, ty = threadIdx.y;
    #pragma unroll
    for (int i = 0; i < 4; i++)
        t[ty + i * 8][tx] = qkv[(size_t)(b * SS + s0 + ty + i * 8) * QKD + 4096 + h * DHH + d0 + tx];
    __syncthreads();
    #pragma unroll
    for (int i = 0; i < 4; i++)
        vt[(size_t)((b * HH + h) * DHH + d0 + ty + i * 8) * SS + s0 + tx] = t[tx][ty + i * 8];
}

// ---------------------------------------------------------------------------
// GEMM: C[M][N] = A[M][K] @ Bt[N][K]^T + bias  (+ epilogue)
// epi 0: store bf16; epi 1: store fp32 (+resid, direct); epi 2: gelu -> bf16
//
// Deep-pipelined schedule (T3+T4+T2+T5):
//   BN=256 fixed, BM in {256,128}; 512 threads = 8 waves (2 M x 4 N).
//   BK=32, FOUR LDS slots per operand (4-deep ring): tile t lives in slot t&3,
//   prefetch issued for tile t+3 during tile t's compute -> a slot is
//   overwritten only 3 tiles after its last read (two joint barriers later),
//   so the in-flight loads are race-free by construction.
//   Counted s_waitcnt vmcnt(2*LPT) ONLY at tile boundaries (never 0 mid-loop),
//   raw s_barrier (no drain) between phases, s_setprio(1) around MFMA cluster.
//   sched_barrier(0) after every s_barrier: raw s_barrier is NOT a compiler
//   memory fence; this pins ds_reads of tile t AFTER the joint barrier that
//   guarantees other waves' staging of tile t completed (vmcnt is per-wave).
//   LDS bank swizzle: 16B-group g' = g ^ ((row>>1)&3), applied on the GLOBAL
//   source address (global_load_lds writes linearly) and on the ds_read addr.
//   Per 8-lane oct this covers all 8 bank-groups -> conflict-free b128 reads.
// ---------------------------------------------------------------------------
template<int BM>
__global__ __launch_bounds__(512, 2) void gemm_bt8(const bf16* __restrict__ A,
                                                   const bf16* __restrict__ Bt,
                                                   const float* __restrict__ bias,
                                                   const float* __restrict__ resid,
                                                   void* __restrict__ Cout,
                                                   int M, int N, int K, int epi) {
    constexpr int BN = 256;
    constexpr int MT = BM / 32;        // m-frags per wave (8 or 4)
    constexpr int MH = MT / 2;         // m-frags per phase
    constexpr int ASLOT = BM * 32;     // elems per A slot
    constexpr int BSLOT = BN * 32;
    __shared__ __align__(16) bf16 smem[4 * (ASLOT + BSLOT)];   // 128 KB / 96 KB
    bf16* As = smem;
    bf16* Bs = smem + 4 * ASLOT;
    float* Es = (float*)smem;          // epilogue overlay (34816 B)

    int tid = threadIdx.x;
    int lane = tid & 63, wave = tid >> 6;
    int quad = lane >> 4, l15 = lane & 15;
    int wm = wave >> 2, wn = wave & 3;

    // XCD-aware bijective block swizzle (gridDim.x % 8 == 0 for all our grids)
    int nbx = N / BN;
    int lin = (int)blockIdx.x;
    int cpx = (int)gridDim.x >> 3;
    lin = (lin & 7) * cpx + (lin >> 3);
    int bx = lin % nbx, by = lin / nbx;
    int bm0 = by * BM, bn0 = bx * BN;

    const bf16* Ag = A + (size_t)bm0 * K;
    const bf16* Bg = Bt + (size_t)bn0 * K;

    // staging coords: linear LDS dest = row*64B + (tid&3)*16B, row = tid>>2
    // source 16B-group pre-swizzled so a swizzled READ sees A[row][quad-chunk]
    int srow = tid >> 2;                         // 0..127
    int grp = (tid & 3) ^ ((srow >> 1) & 3);
    const bf16* aSrc0 = Ag + (size_t)srow * K + grp * 8;
    const bf16* aSrc1 = Ag + (size_t)(128 + srow) * K + grp * 8;   // unused if BM==128
    const bf16* bSrc0 = Bg + (size_t)srow * K + grp * 8;
    const bf16* bSrc1 = Bg + (size_t)(128 + srow) * K + grp * 8;

    int T = K / 32;

    auto stA0 = [&](int t) { gl2lds16(aSrc0 + t * 32, As + (t & 3) * ASLOT + wave * 512); };
    auto stA1 = [&](int t) { gl2lds16(aSrc1 + t * 32, As + (t & 3) * ASLOT + 4096 + wave * 512); };
    auto stB0 = [&](int t) { gl2lds16(bSrc0 + t * 32, Bs + (t & 3) * BSLOT + wave * 512); };
    auto stB1 = [&](int t) { gl2lds16(bSrc1 + t * 32, Bs + (t & 3) * BSLOT + 4096 + wave * 512); };

    // prologue: stage tiles 0,1,2 fully; wait until tile 0 landed (2 tiles in flight)
    #pragma unroll
    for (int u = 0; u < 3; u++) {
        if constexpr (BM == 256) { stA0(u); stA1(u); stB0(u); stB1(u); }
        else                     { stA0(u); stB0(u); stB1(u); }
    }
    if constexpr (BM == 256) asm volatile("s_waitcnt vmcnt(8)" ::: "memory");
    else                     asm volatile("s_waitcnt vmcnt(6)" ::: "memory");
    __builtin_amdgcn_s_barrier();
    __builtin_amdgcn_sched_barrier(0);

    f32x4 acc[MT][4] = {};
    int goff = (quad ^ ((l15 >> 1) & 3)) * 8;            // swizzled 16B-group
    int aro = (wm * (BM / 2) + l15) * 32 + goff;
    int bro = (wn * 64 + l15) * 32 + goff;

    for (int t = 0; t < T; ++t) {
        const bf16* AsS = As + (t & 3) * ASLOT;
        const bf16* BsS = Bs + (t & 3) * BSLOT;
        int u = t + 3;
        bf16x8 af[MH], bfr[4];

        // ---- phase 0: A(0..MH-1)+B reads, stage 2, MFMA upper half ----
        #pragma unroll
        for (int m = 0; m < MH; m++)
            af[m] = *(const bf16x8*)(const void*)&AsS[aro + m * 512];
        #pragma unroll
        for (int n = 0; n < 4; n++)
            bfr[n] = *(const bf16x8*)(const void*)&BsS[bro + n * 512];
        if (u < T) {
            if constexpr (BM == 256) { stA0(u); stA1(u); }
            else                     { stA0(u); stB0(u); }
        }
        __builtin_amdgcn_s_barrier();
        __builtin_amdgcn_sched_barrier(0);
        __builtin_amdgcn_s_setprio(1);
        #pragma unroll
        for (int m = 0; m < MH; m++)
            #pragma unroll
            for (int n = 0; n < 4; n++)
                acc[m][n] = __builtin_amdgcn_mfma_f32_16x16x32_bf16(af[m], bfr[n], acc[m][n], 0, 0, 0);
        __builtin_amdgcn_s_setprio(0);
        __builtin_amdgcn_s_barrier();
        __builtin_amdgcn_sched_barrier(0);

        // ---- phase 1: A(MH..MT-1) reads, stage rest, MFMA lower half ----
        #pragma unroll
        for (int m = 0; m < MH; m++)
            af[m] = *(const bf16x8*)(const void*)&AsS[aro + (MH + m) * 512];
        if (u < T) {
            if constexpr (BM == 256) { stB0(u); stB1(u); }
            else                     { stB1(u); }
        }
        __builtin_amdgcn_s_barrier();
        __builtin_amdgcn_sched_barrier(0);
        __builtin_amdgcn_s_setprio(1);
        #pragma unroll
        for (int m = 0; m < MH; m++)
            #pragma unroll
            for (int n = 0; n < 4; n++)
                acc[MH + m][n] = __builtin_amdgcn_mfma_f32_16x16x32_bf16(af[m], bfr[n], acc[MH + m][n], 0, 0, 0);
        __builtin_amdgcn_s_setprio(0);

        // ---- tile boundary: counted wait (steady 2*LPT in flight), then joint barrier ----
        if (t < T - 3) {
            if constexpr (BM == 256) asm volatile("s_waitcnt vmcnt(8)" ::: "memory");
            else                     asm volatile("s_waitcnt vmcnt(6)" ::: "memory");
        } else if (t == T - 3) {
            if constexpr (BM == 256) asm volatile("s_waitcnt vmcnt(4)" ::: "memory");
            else                     asm volatile("s_waitcnt vmcnt(3)" ::: "memory");
        } else if (t == T - 2) {
            asm volatile("s_waitcnt vmcnt(0)" ::: "memory");
        }
        __builtin_amdgcn_s_barrier();
        __builtin_amdgcn_sched_barrier(0);
    }

    __syncthreads();   // full drain before LDS reuse as epilogue buffer

    if (epi == 1) {
        // fp32 + residual, direct C-layout stores (64 B contiguous per quad)
        #pragma unroll
        for (int nt = 0; nt < 4; nt++) {
            int col = bn0 + wn * 64 + nt * 16 + l15;
            float bv = bias[col];
            #pragma unroll
            for (int mt = 0; mt < MT; mt++)
                #pragma unroll
                for (int r = 0; r < 4; r++) {
                    int row = bm0 + wm * (BM / 2) + mt * 16 + quad * 4 + r;
                    size_t idx = (size_t)row * N + col;
                    ((float*)Cout)[idx] = acc[mt][nt][r] + bv + resid[idx];
                }
        }
    } else {
        // bf16 out: LDS repack -> full-line 32B/lane stores
        float bv[4];
        #pragma unroll
        for (int nt = 0; nt < 4; nt++) bv[nt] = bias[bn0 + wn * 64 + nt * 16 + l15];
        int rr = lane >> 2, cc = lane & 3;
        #pragma unroll
        for (int mt = 0; mt < MT; mt++) {
            #pragma unroll
            for (int nt = 0; nt < 4; nt++)
                #pragma unroll
                for (int r = 0; r < 4; r++)
                    Es[wave * 1088 + (quad * 4 + r) * 68 + nt * 16 + l15] = acc[mt][nt][r] + bv[nt];
            asm volatile("s_waitcnt lgkmcnt(0)" ::: "memory");
            __builtin_amdgcn_sched_barrier(0);
            float vals[16];
            #pragma unroll
            for (int j4 = 0; j4 < 4; j4++) {
                float4 f = *(const float4*)&Es[wave * 1088 + rr * 68 + cc * 16 + j4 * 4];
                vals[j4 * 4 + 0] = f.x; vals[j4 * 4 + 1] = f.y;
                vals[j4 * 4 + 2] = f.z; vals[j4 * 4 + 3] = f.w;
            }
            asm volatile("s_waitcnt lgkmcnt(0)" ::: "memory");
            __builtin_amdgcn_sched_barrier(0);
            union { bf16 h[16]; uint4 u4[2]; } ob;
            #pragma unroll
            for (int j = 0; j < 16; j++) {
                float v = vals[j];
                if (epi == 2) v = 0.5f * v * (1.0f + erff(v * 0.70710678118654752f));
                ob.h[j] = __float2bfloat16(v);
            }
            int grow = bm0 + wm * (BM / 2) + mt * 16 + rr;
            int gcol = bn0 + wn * 64 + cc * 16;
            uint4* dst = (uint4*)((bf16*)Cout + (size_t)grow * N + gcol);
            dst[0] = ob.u4[0];
            dst[1] = ob.u4[1];
        }
    }
}

// ---------------------------------------------------------------------------
// Flash attention: grid (S/128, H, B), 512 threads (8 waves).
// ---------------------------------------------------------------------------
__global__ __launch_bounds__(512) void flash_attn(const bf16* __restrict__ qkv,
                                                  const bf16* __restrict__ vt,
                                                  bf16* __restrict__ out) {
    __shared__ __align__(16) bf16 Qs[128 * 128];
    __shared__ __align__(16) bf16 Ks[128 * 128];
    __shared__ __align__(16) bf16 Vs[128 * 128];   // [dh][key]
    __shared__ __align__(16) bf16 Ps[8 * 16 * 128];
    int tid = threadIdx.x;
    int lane = tid & 63, wave = tid >> 6;
    int quad = lane >> 4, l15 = lane & 15;
    int xr = blockIdx.x;
    int t = (xr & 1) ? (15 - (xr >> 1)) : (xr >> 1);
    int q0 = t * 128;
    int h = blockIdx.y, b = blockIdx.z;
    int jlast = t;
    const float scale = 0.088388347648318447f;  // 1/sqrt(128)

    int srow = tid >> 4;                    // 0..31
    int sgrp = (tid & 15) ^ (srow & 15);    // swizzled source 16B-group

    const bf16* qb = qkv + h * DHH;
    const bf16* kb = qkv + 2048 + h * DHH;

    #pragma unroll
    for (int i = 0; i < 4; i++) {
        int row = i * 32 + srow;
        gl2lds16(qb + (size_t)(b * SS + q0 + row) * QKD + sgrp * 8,
                 Qs + i * 4096 + wave * 512);
    }

    f32x4 oacc[8] = {};
    float mrun[4] = {-1e30f, -1e30f, -1e30f, -1e30f};
    float lrun[4] = {0.f, 0.f, 0.f, 0.f};

    for (int j = 0; j <= jlast; j++) {
        __syncthreads();
        #pragma unroll
        for (int i = 0; i < 4; i++) {
            int row = i * 32 + srow;
            gl2lds16(kb + (size_t)(b * SS + j * 128 + row) * QKD + sgrp * 8,
                     Ks + i * 4096 + wave * 512);
        }
        #pragma unroll
        for (int i = 0; i < 4; i++) {
            int row = i * 32 + srow;
            gl2lds16(vt + (size_t)((b * HH + h) * DHH + row) * SS + j * 128 + sgrp * 8,
                     Vs + i * 4096 + wave * 512);
        }
        __syncthreads();

        f32x4 sacc[8] = {};
        bf16x8 aq[4];
        #pragma unroll
        for (int kc = 0; kc < 4; kc++)
            aq[kc] = *(const bf16x8*)(const void*)&Qs[(wave * 16 + l15) * 128 + (((kc * 4 + quad) ^ l15) * 8)];
        #pragma unroll
        for (int n = 0; n < 8; n++)
            #pragma unroll
            for (int kc = 0; kc < 4; kc++) {
                bf16x8 bk = *(const bf16x8*)(const void*)&Ks[(n * 16 + l15) * 128 + (((kc * 4 + quad) ^ l15) * 8)];
                sacc[n] = __builtin_amdgcn_mfma_f32_16x16x32_bf16(aq[kc], bk, sacc[n], 0, 0, 0);
            }

        float mx[4] = {-1e30f, -1e30f, -1e30f, -1e30f};
        #pragma unroll
        for (int n = 0; n < 8; n++)
            #pragma unroll
            for (int r = 0; r < 4; r++) {
                float v = sacc[n][r] * scale;
                if (j == jlast) {
                    int kl = n * 16 + l15;
                    int ql = wave * 16 + quad * 4 + r;
                    if (kl > ql) v = -1e30f;
                }
                sacc[n][r] = v;
                mx[r] = fmaxf(mx[r], v);
            }
        #pragma unroll
        for (int r = 0; r < 4; r++) {
            mx[r] = fmaxf(mx[r], __shfl_xor(mx[r], 1));
            mx[r] = fmaxf(mx[r], __shfl_xor(mx[r], 2));
            mx[r] = fmaxf(mx[r], __shfl_xor(mx[r], 4));
            mx[r] = fmaxf(mx[r], __shfl_xor(mx[r], 8));
        }
        float alpha[4], rsum[4];
        #pragma unroll
        for (int r = 0; r < 4; r++) {
            float mn = fmaxf(mrun[r], mx[r]);
            alpha[r] = __expf(mrun[r] - mn);
            mrun[r] = mn;
            rsum[r] = 0.f;
        }
        #pragma unroll
        for (int n = 0; n < 8; n++)
            #pragma unroll
            for (int r = 0; r < 4; r++) {
                float p = __expf(sacc[n][r] - mrun[r]);
                sacc[n][r] = p;
                rsum[r] += p;
            }
        #pragma unroll
        for (int r = 0; r < 4; r++) {
            rsum[r] += __shfl_xor(rsum[r], 1);
            rsum[r] += __shfl_xor(rsum[r], 2);
            rsum[r] += __shfl_xor(rsum[r], 4);
            rsum[r] += __shfl_xor(rsum[r], 8);
            lrun[r] = lrun[r] * alpha[r] + rsum[r];
        }
        #pragma unroll
        for (int n = 0; n < 8; n++)
            #pragma unroll
            for (int r = 0; r < 4; r++)
                oacc[n][r] *= alpha[r];

        #pragma unroll
        for (int n = 0; n < 8; n++)
            #pragma unroll
            for (int r = 0; r < 4; r++) {
                int rowp = quad * 4 + r;
                int g = 2 * n + (l15 >> 3);
                Ps[wave * 2048 + rowp * 128 + ((g ^ rowp) * 8) + (l15 & 7)] =
                    __float2bfloat16(sacc[n][r]);
            }
        asm volatile("s_waitcnt lgkmcnt(0)" ::: "memory");
        __builtin_amdgcn_sched_barrier(0);

        bf16x8 ap[4];
        #pragma unroll
        for (int kc = 0; kc < 4; kc++)
            ap[kc] = *(const bf16x8*)(const void*)&Ps[wave * 2048 + l15 * 128 + (((kc * 4 + quad) ^ l15) * 8)];
        #pragma unroll
        for (int n = 0; n < 8; n++)
            #pragma unroll
            for (int kc = 0; kc < 4; kc++) {
                bf16x8 bv = *(const bf16x8*)(const void*)&Vs[(n * 16 + l15) * 128 + (((kc * 4 + quad) ^ l15) * 8)];
                oacc[n] = __builtin_amdgcn_mfma_f32_16x16x32_bf16(ap[kc], bv, oacc[n], 0, 0, 0);
            }
    }

    #pragma unroll
    for (int n = 0; n < 8; n++)
        #pragma unroll
        for (int r = 0; r < 4; r++) {
            float v = oacc[n][r] / lrun[r];
            out[(size_t)(b * SS + q0 + wave * 16 + quad * 4 + r) * DD + h * DHH + n * 16 + l15] =
                __float2bfloat16(v);
        }
}

// ---------------------------------------------------------------------------
extern "C" void kernel_launch(void* const* d_in, const int* in_sizes, int n_in,
                              void* d_out, int out_size, void* d_ws, size_t ws_size,
                              hipStream_t stream) {
    (void)in_sizes; (void)n_in; (void)out_size; (void)ws_size;
    const float* x     = (const float*)d_in[0];
    const float* ln1_g = (const float*)d_in[2];
    const float* ln1_b = (const float*)d_in[3];
    const float* wq    = (const float*)d_in[4];
    const float* bq    = (const float*)d_in[5];
    const float* wk    = (const float*)d_in[6];
    const float* bk    = (const float*)d_in[7];
    const float* wv    = (const float*)d_in[8];
    const float* bv    = (const float*)d_in[9];
    const float* wo    = (const float*)d_in[10];
    const float* bo    = (const float*)d_in[11];
    const float* ln2_g = (const float*)d_in[12];
    const float* ln2_b = (const float*)d_in[13];
    const float* w_in  = (const float*)d_in[14];
    const float* b_in  = (const float*)d_in[15];
    const float* w_out = (const float*)d_in[16];
    const float* b_out = (const float*)d_in[17];
    float* out = (float*)d_out;

    char* ws = (char*)d_ws;
    const size_t MB = 1024 * 1024;
    bf16*  wt   = (bf16*)(ws + 0 * MB);     // 32 MB
    bf16*  xn   = (bf16*)(ws + 32 * MB);    // 16 MB (LN1 out; later att; later xn2)
    bf16*  qkvb = (bf16*)(ws + 48 * MB);    // 48 MB fused qkv [token][6144]
    bf16*  vtb  = (bf16*)(ws + 96 * MB);    // 16 MB
    float* x1   = (float*)(ws + 112 * MB);  // 32 MB
    float* bcat = (float*)(ws + 144 * MB);  // 24 KB
    bf16*  hb   = (bf16*)(ws + 48 * MB);    // 64 MB (reuses qkvb+vtb after attention)
    bf16*  att  = xn;
    bf16*  xn2  = xn;

    dim3 t256(256), t32x8(32, 8), t512(512);

    // LN1
    ln_kernel<<<MM, t256, 0, stream>>>(x, ln1_g, ln1_b, xn);

    // fused QKV: wt = [wq^T ; wk^T ; wv^T] (6144 x 2048)
    transpose_cast<<<dim3(DD / 32, DD / 32), t32x8, 0, stream>>>(wq, wt, DD, DD);
    transpose_cast<<<dim3(DD / 32, DD / 32), t32x8, 0, stream>>>(wk, wt + 2048 * 2048, DD, DD);
    transpose_cast<<<dim3(DD / 32, DD / 32), t32x8, 0, stream>>>(wv, wt + 2 * 2048 * 2048, DD, DD);
    concat3<<<QKD / 256, t256, 0, stream>>>(bq, bk, bv, bcat);
    // grid = (6144/256)*(4096/256) = 384
    gemm_bt8<256><<<dim3(384), t512, 0, stream>>>(xn, wt, bcat, nullptr, qkvb, MM, QKD, DD, 0);

    // V transpose per head
    transpose_v<<<dim3(SS / 32, DHH / 32, BB * HH), t32x8, 0, stream>>>(qkvb, vtb);

    // attention -> att ([token][D] bf16)
    flash_attn<<<dim3(SS / 128, HH, BB), t512, 0, stream>>>(qkvb, vtb, att);

    // x1 = x + att @ wo + bo   (N=2048 -> BM=128, grid = 8*32 = 256)
    transpose_cast<<<dim3(DD / 32, DD / 32), t32x8, 0, stream>>>(wo, wt, DD, DD);
    gemm_bt8<128><<<dim3(256), t512, 0, stream>>>(att, wt, bo, x, x1, MM, DD, DD, 1);

    // LN2
    ln_kernel<<<MM, t256, 0, stream>>>(x1, ln2_g, ln2_b, xn2);

    // h = gelu(xn2 @ w_in + b_in)   grid = 32*16 = 512
    transpose_cast<<<dim3(DFF / 32, DD / 32), t32x8, 0, stream>>>(w_in, wt, DD, DFF);
    gemm_bt8<256><<<dim3(512), t512, 0, stream>>>(xn2, wt, b_in, nullptr, hb, MM, DFF, DD, 2);

    // out = x1 + h @ w_out + b_out  (N=2048 -> BM=128, grid = 256)
    transpose_cast<<<dim3(DD / 32, DFF / 32), t32x8, 0, stream>>>(w_out, wt, DFF, DD);
    gemm_bt8<128><<<dim3(256), t512, 0, stream>>>(hb, wt, b_out, x1, out, MM, DD, DFF, 1);
}